// Round 1
// baseline (1001.592 us; speedup 1.0000x reference)
//
#include <hip/hip_runtime.h>

// Problem constants (from reference setup_inputs):
//   B=4, H=8, M=2048, K=2048, N=64, NNZ = B*H*M*64 = 4,194,304
// out[bh, m, :] += values[i] * b[bh, idx_k[i], :]  for each nonzero i
constexpr int N_COLS = 64;
constexpr int K_DIM  = 2048;
constexpr int M_DIM  = 2048;

// One wave (64 lanes) per nonzero; lane = output column.
// Index/value loads are wave-uniform (broadcast); gather and scatter are
// fully coalesced 256B accesses. Scatter via fp32 atomicAdd (device scope,
// order-independent => matches segment_sum semantics in fp32).
__global__ void spmm_coo_atomic(const float* __restrict__ values,
                                const float* __restrict__ b,
                                const int*   __restrict__ idx_bh,
                                const int*   __restrict__ idx_m,
                                const int*   __restrict__ idx_k,
                                float*       __restrict__ out,
                                int nnz) {
    long long gid = (long long)blockIdx.x * blockDim.x + threadIdx.x;
    int nz   = (int)(gid >> 6);
    int lane = (int)(gid & 63);
    if (nz >= nnz) return;

    int   bh = idx_bh[nz];
    int   m  = idx_m[nz];
    int   k  = idx_k[nz];
    float v  = values[nz];

    float bval = b[((size_t)bh * K_DIM + k) * N_COLS + lane];
    atomicAdd(&out[((size_t)bh * M_DIM + m) * N_COLS + lane], v * bval);
}

extern "C" void kernel_launch(void* const* d_in, const int* in_sizes, int n_in,
                              void* d_out, int out_size, void* d_ws, size_t ws_size,
                              hipStream_t stream) {
    const float* values = (const float*)d_in[0];
    const float* b      = (const float*)d_in[1];
    const int*   idx_bh = (const int*)d_in[2];
    const int*   idx_m  = (const int*)d_in[3];
    const int*   idx_k  = (const int*)d_in[4];
    float*       out    = (float*)d_out;

    const int nnz = in_sizes[0];

    // Harness poisons d_out with 0xAA before every call — zero it first.
    hipMemsetAsync(d_out, 0, (size_t)out_size * sizeof(float), stream);

    const long long total_threads = (long long)nnz * N_COLS;
    const int block = 256;
    const long long grid = (total_threads + block - 1) / block;
    spmm_coo_atomic<<<(dim3)(unsigned)grid, block, 0, stream>>>(
        values, b, idx_bh, idx_m, idx_k, out, nnz);
}

// Round 2
// 679.892 us; speedup vs baseline: 1.4732x; 1.4732x over previous
//
#include <hip/hip_runtime.h>

// Problem constants (from reference setup_inputs):
//   B=4, H=8, M=2048, K=2048, N=64, NNZ = B*H*M*64 = 4,194,304
// out[bh, m, :] = sum_i values[i] * b[bh, idx_k[i], :]  over nnz with that (bh,m)
constexpr int N_COLS = 64;
constexpr int K_DIM  = 2048;
constexpr int M_DIM  = 2048;
constexpr int SEGS   = 32 * 2048;   // BH * M = 65536 output rows (segments)
constexpr int SCAN_T = 1024;        // threads in the single-block scan
constexpr int PER_T  = SEGS / SCAN_T;  // 64 counts per scan thread

struct Pair { float v; int k; };    // 8B packed (value, k-index)

// ---------- fallback (round-1 baseline): wave-per-nnz atomic scatter ----------
__global__ void spmm_coo_atomic(const float* __restrict__ values,
                                const float* __restrict__ b,
                                const int*   __restrict__ idx_bh,
                                const int*   __restrict__ idx_m,
                                const int*   __restrict__ idx_k,
                                float*       __restrict__ out,
                                int nnz) {
    long long gid = (long long)blockIdx.x * blockDim.x + threadIdx.x;
    int nz   = (int)(gid >> 6);
    int lane = (int)(gid & 63);
    if (nz >= nnz) return;
    int   bh = idx_bh[nz];
    int   m  = idx_m[nz];
    int   k  = idx_k[nz];
    float v  = values[nz];
    float bval = b[((size_t)bh * K_DIM + k) * N_COLS + lane];
    atomicAdd(&out[((size_t)bh * M_DIM + m) * N_COLS + lane], v * bval);
}

// ---------- phase 1: histogram of segment ids ----------
__global__ void hist_kernel(const int* __restrict__ idx_bh,
                            const int* __restrict__ idx_m,
                            int* __restrict__ counts, int nnz) {
    int i = blockIdx.x * blockDim.x + threadIdx.x;
    if (i >= nnz) return;
    int seg = idx_bh[i] * M_DIM + idx_m[i];
    atomicAdd(&counts[seg], 1);
}

// ---------- phase 2: single-block exclusive scan of SEGS counts ----------
// counts (== cursor array) is read, then off[] and cursor[] written.
__global__ void scan_kernel(int* __restrict__ cursor,   // in: counts, out: running offsets copy
                            int* __restrict__ off,      // out: exclusive offsets, off[SEGS] = nnz
                            int nnz) {
    __shared__ int partial[SCAN_T];
    int t = threadIdx.x;
    int base = t * PER_T;
    int s = 0;
    for (int i = 0; i < PER_T; ++i) s += cursor[base + i];
    partial[t] = s;
    __syncthreads();
    // Hillis-Steele inclusive scan over SCAN_T partials
    for (int d = 1; d < SCAN_T; d <<= 1) {
        int v = (t >= d) ? partial[t - d] : 0;
        __syncthreads();
        partial[t] += v;
        __syncthreads();
    }
    int run = (t == 0) ? 0 : partial[t - 1];
    for (int i = 0; i < PER_T; ++i) {
        int idx = base + i;
        int c = cursor[idx];
        off[idx]    = run;
        cursor[idx] = run;   // scatter-phase cursor starts at segment offset
        run += c;
    }
    if (t == SCAN_T - 1) off[SEGS] = run;   // == nnz
}

// ---------- phase 3: scatter nonzeros into segment-sorted order ----------
__global__ void scatter_kernel(const float* __restrict__ values,
                               const int*   __restrict__ idx_bh,
                               const int*   __restrict__ idx_m,
                               const int*   __restrict__ idx_k,
                               int*  __restrict__ cursor,
                               Pair* __restrict__ packed, int nnz) {
    int i = blockIdx.x * blockDim.x + threadIdx.x;
    if (i >= nnz) return;
    int seg = idx_bh[i] * M_DIM + idx_m[i];
    int pos = atomicAdd(&cursor[seg], 1);
    Pair p; p.v = values[i]; p.k = idx_k[i];
    packed[pos] = p;
}

// ---------- phase 4: one wave per segment, register accumulate, single store ----------
__global__ void accum_kernel(const Pair* __restrict__ packed,
                             const int*  __restrict__ off,
                             const float* __restrict__ b,
                             float* __restrict__ out) {
    int wave_in_block = threadIdx.x >> 6;
    int lane = threadIdx.x & 63;
    int seg  = blockIdx.x * (blockDim.x >> 6) + wave_in_block;
    if (seg >= SEGS) return;

    int start = off[seg];
    int end   = off[seg + 1];
    int bh    = seg >> 11;                       // seg / M_DIM
    const float* bslab = b + (size_t)bh * K_DIM * N_COLS;

    float acc0 = 0.f, acc1 = 0.f;
    for (int base = start; base < end; base += 64) {
        int n = end - base; if (n > 64) n = 64;
        Pair p; p.v = 0.f; p.k = 0;
        if (lane < n) p = packed[base + lane];   // coalesced 512B per wave
        int j = 0;
        for (; j + 1 < n; j += 2) {
            float v0 = __shfl(p.v, j);     int k0 = __shfl(p.k, j);
            float v1 = __shfl(p.v, j + 1); int k1 = __shfl(p.k, j + 1);
            float b0 = bslab[(size_t)k0 * N_COLS + lane];
            float b1 = bslab[(size_t)k1 * N_COLS + lane];
            acc0 += v0 * b0;
            acc1 += v1 * b1;
        }
        if (j < n) {
            float v0 = __shfl(p.v, j); int k0 = __shfl(p.k, j);
            acc0 += v0 * bslab[(size_t)k0 * N_COLS + lane];
        }
    }
    out[(size_t)seg * N_COLS + lane] = acc0 + acc1;   // covers empty segments with 0
}

extern "C" void kernel_launch(void* const* d_in, const int* in_sizes, int n_in,
                              void* d_out, int out_size, void* d_ws, size_t ws_size,
                              hipStream_t stream) {
    const float* values = (const float*)d_in[0];
    const float* b      = (const float*)d_in[1];
    const int*   idx_bh = (const int*)d_in[2];
    const int*   idx_m  = (const int*)d_in[3];
    const int*   idx_k  = (const int*)d_in[4];
    float*       out    = (float*)d_out;
    const int    nnz    = in_sizes[0];

    // workspace layout: [ off: (SEGS+1) ints | cursor: SEGS ints | pad | packed: nnz Pairs ]
    const size_t packed_off = 1u << 20;  // 1 MiB (off+cursor need ~513 KiB)
    const size_t needed = packed_off + (size_t)nnz * sizeof(Pair);

    if (ws_size < needed) {
        // not enough scratch: fall back to correct atomic version
        hipMemsetAsync(d_out, 0, (size_t)out_size * sizeof(float), stream);
        long long total = (long long)nnz * N_COLS;
        spmm_coo_atomic<<<(unsigned)((total + 255) / 256), 256, 0, stream>>>(
            values, b, idx_bh, idx_m, idx_k, out, nnz);
        return;
    }

    int*  off    = (int*)d_ws;
    int*  cursor = off + (SEGS + 1);
    Pair* packed = (Pair*)((char*)d_ws + packed_off);

    // zero the histogram counters (cursor doubles as counts)
    hipMemsetAsync(cursor, 0, (size_t)SEGS * sizeof(int), stream);

    const int block = 256;
    const int nz_blocks = (nnz + block - 1) / block;

    hist_kernel<<<nz_blocks, block, 0, stream>>>(idx_bh, idx_m, cursor, nnz);
    scan_kernel<<<1, SCAN_T, 0, stream>>>(cursor, off, nnz);
    scatter_kernel<<<nz_blocks, block, 0, stream>>>(values, idx_bh, idx_m, idx_k,
                                                    cursor, packed, nnz);
    // 4 waves per block, one segment per wave
    accum_kernel<<<SEGS / 4, 256, 0, stream>>>(packed, off, b, out);
}